// Round 4
// baseline (96.406 us; speedup 1.0000x reference)
//
#include <hip/hip_runtime.h>

#define N_REGIONS 17
#define N_CH 7
#define ROWS_ 82
#define COLS_ 67
#define N_MAP (ROWS_ * COLS_)        // 5494 cells in the grid
#define EPB (N_MAP * N_CH)           // 38458 floats per batch (== 2 mod 4)
#define PAIR (2 * EPB)               // 76916 floats per 2 batches (== 0 mod 4)
#define PAIR4 (PAIR / 4)             // 19229 float4s per pair
#define HALF4 9615                   // first-half float4 count (second half = 9614)
#define XROW (N_REGIONS * N_CH)      // 119 floats per batch of x
#define XPAIR (2 * XROW)             // 238 floats of x per pair

typedef float f32x4 __attribute__((ext_vector_type(4)));

// total output = 2048 * 38458 = 1024 * 76916 = 78,761,984 floats (exact)

__global__ void init_table_k(short* __restrict__ t) {
    int i = blockIdx.x * blockDim.x + threadIdx.x;
    if (i < PAIR) t[i] = -1;
}

__global__ void scatter_table_k(const int* __restrict__ cell_lin,
                                const int* __restrict__ region_ids,
                                int n, short* __restrict__ t) {
    int i = blockIdx.x * blockDim.x + threadIdx.x;
    if (i >= n) return;
    int c = cell_lin[i];
    int r = region_ids[i];
    if (c < 0 || c >= N_MAP) return;
#pragma unroll
    for (int lb = 0; lb < 2; ++lb) {
        int dst = lb * EPB + c * N_CH;
        short src = (short)(lb * XROW + r * N_CH);
#pragma unroll
        for (int ch = 0; ch < N_CH; ++ch) t[dst + ch] = (short)(src + ch);
    }
}

// One block per (pair, half). x[pair] staged in LDS; gathers hit LDS, not L1/TA.
__global__ __launch_bounds__(256) void fill3_k(const float* __restrict__ x,
                                               const short* __restrict__ t,
                                               float* __restrict__ out) {
    __shared__ float xs[XPAIR];
    unsigned pair = blockIdx.x >> 1;
    unsigned half = blockIdx.x & 1;
    unsigned tid = threadIdx.x;
    if (tid < XPAIR) xs[tid] = x[pair * XPAIR + tid];
    __syncthreads();

    unsigned start = half ? HALF4 : 0;
    unsigned end   = half ? PAIR4 : HALF4;
    float* outp = out + (size_t)pair * PAIR;
    for (unsigned i = start + tid; i < end; i += 256) {
        unsigned e0 = i * 4u;
        short4 s = *reinterpret_cast<const short4*>(t + e0);   // 8B, L2-resident
        f32x4 v;
        v.x = (s.x >= 0) ? xs[s.x] : 0.0f;
        v.y = (s.y >= 0) ? xs[s.y] : 0.0f;
        v.z = (s.z >= 0) ? xs[s.z] : 0.0f;
        v.w = (s.w >= 0) ? xs[s.w] : 0.0f;
        __builtin_nontemporal_store(v, reinterpret_cast<f32x4*>(outp + e0));
    }
}

extern "C" void kernel_launch(void* const* d_in, const int* in_sizes, int n_in,
                              void* d_out, int out_size, void* d_ws, size_t ws_size,
                              hipStream_t stream) {
    const float* x        = (const float*)d_in[0];
    const int* cell_lin   = (const int*)d_in[1];
    const int* region_ids = (const int*)d_in[2];
    float* out = (float*)d_out;
    short* table = (short*)d_ws;          // 76916 * 2 B = 150 KB of scratch
    int n_cells = in_sizes[1];

    init_table_k<<<(PAIR + 255) / 256, 256, 0, stream>>>(table);
    scatter_table_k<<<(n_cells + 255) / 256, 256, 0, stream>>>(cell_lin, region_ids, n_cells, table);

    fill3_k<<<2048, 256, 0, stream>>>(x, table, out);
}